// Round 2
// baseline (491.467 us; speedup 1.0000x reference)
//
#include <hip/hip_runtime.h>

// RandomShiftsAug: out[n,c,i,j] = x[n,c, clamp(i+sy-4,0,127), clamp(j+sx-4,0,127)]
// (bilinear grid_sample degenerates to an integer shift: shifts are integral
// multiples of 2/Hp on pixel centers of the padded image).
//
// Streaming-BW kernel: 604 MB total traffic, floor ~96 us @ 6.3 TB/s.
// This version: 8 floats/thread, non-temporal loads+stores (no reuse,
// footprint >> 256 MiB LLC), branch-free interior path.

#define NN   512
#define CC   9
#define HH   128
#define PADV 4

// native clang vector type — required by __builtin_nontemporal_{load,store}
typedef float vfloat4 __attribute__((ext_vector_type(4)));

__global__ __launch_bounds__(256) void shift_copy_kernel(
    const float* __restrict__ x,
    const int*   __restrict__ shift,
    float*       __restrict__ out)
{
    // One thread = 8 consecutive output columns (2x float4 nt-store).
    // tid layout: (((n*CC + c)*HH + i)*16 + jt), j = jt*8
    int tid  = blockIdx.x * blockDim.x + threadIdx.x;
    int jt   = tid & 15;          // 128/8 = 16 vectors per row
    int rest = tid >> 4;
    int i    = rest & (HH - 1);
    rest >>= 7;
    int c    = rest % CC;
    int n    = rest / CC;
    if (n >= NN) return;

    int sx = shift[2 * n + 0] - PADV;   // column (x) shift, in [-4, 4]
    int sy = shift[2 * n + 1] - PADV;   // row    (y) shift, in [-4, 4]

    int ry = i + sy;
    ry = ry < 0 ? 0 : (ry > HH - 1 ? HH - 1 : ry);

    const float* __restrict__ xrow =
        x + ((size_t)(n * CC + c) * HH + ry) * HH;

    int j0 = jt * 8 + sx;

    float v[8];
    if (j0 >= 0 && j0 <= HH - 8) {
        // interior: contiguous, no clamping needed (14/16 lanes always;
        // 16/16 when sx == 0)
        #pragma unroll
        for (int k = 0; k < 8; ++k)
            v[k] = __builtin_nontemporal_load(xrow + j0 + k);
    } else {
        // edge lanes (jt==0 with sx<0, jt==15 with sx>0): clamp per element
        #pragma unroll
        for (int k = 0; k < 8; ++k) {
            int r = j0 + k;
            r = r < 0 ? 0 : (r > HH - 1 ? HH - 1 : r);
            v[k] = xrow[r];
        }
    }

    float* op = out + ((size_t)(n * CC + c) * HH + i) * HH + jt * 8;
    vfloat4 a = {v[0], v[1], v[2], v[3]};
    vfloat4 b = {v[4], v[5], v[6], v[7]};
    __builtin_nontemporal_store(a, (vfloat4*)op);
    __builtin_nontemporal_store(b, (vfloat4*)(op + 4));
}

extern "C" void kernel_launch(void* const* d_in, const int* in_sizes, int n_in,
                              void* d_out, int out_size, void* d_ws, size_t ws_size,
                              hipStream_t stream)
{
    const float* x     = (const float*)d_in[0];
    const int*   shift = (const int*)d_in[1];
    float*       out   = (float*)d_out;

    // total threads = N*C*H*(H/8) = 512*9*128*16 = 9,437,184
    const int total_threads = NN * CC * HH * (HH / 8);
    const int block = 256;
    const int grid  = (total_threads + block - 1) / block;   // 36864

    shift_copy_kernel<<<grid, block, 0, stream>>>(x, shift, out);
}